// Round 5
// baseline (454.475 us; speedup 1.0000x reference)
//
#include <hip/hip_runtime.h>

#define B_    8
#define N1_   16384
#define N2_   4096
#define NTOT_ (B_ * N1_)

typedef float v2f __attribute__((ext_vector_type(2)));

// ---------------------------------------------------------------------------
// GOLD SEMANTICS (verified R12/R13, absmax 0.015625 = bf16 output floor):
//   s  = ((x*x + y*y) + z*z)          plain forward, no fma
//   dot= fma(x,x', fma(y,y', z*z'))   z-first FMA chain (numpy AVX2 einsum)
//   d2 = fma(-2, dot, s1+s2)          bitwise == plain (s1+s2) - 2*dot
//   w  : r = 1/(d2+1e-8), w = r/((r0+r1)+r2), plain f32
// R19: measured lesson from R17/R18: ANY cmp->select index tracking in the
// hot scan compiles 2-3x fat; only pure v_min/v_max float chains compile
// 1:1. So: TWO-PASS.
//   Pass 1 (values only): packed v_pk dists + 9-op min/max merge network ->
//     exact gold 3rd-smallest value `thr`. No compares, no masks.
//   Pass 2 (indices): rescan; wave-uniform guard __any(min(t0,t1)<=thr)
//     (taken ~17% at 2048-cand chunks); inside, replay the ORIGINAL gold
//     ins3 over the hit superset in ascending j == bit-exact gold triple
//     (spurious >thr entries provably pushed out; >=3 true hits exist).
// Chunks of 2048 cands (2 per batch): 1024 blocks, 4 waves/SIMD, 32KB LDS.
// ---------------------------------------------------------------------------
__device__ __forceinline__ float np_sumsq(float x, float y, float z)
{
#pragma clang fp contract(off)
    return ((x * x + y * y) + z * z);   // forward, plain (no contraction)
}

// gold top-3 insert (strict <, stable ascending-j ties) — rare-path only
__device__ __forceinline__ void ins3(const float t, const int jj,
    float& d0, float& d1, float& d2v, int& i0, int& i1, int& i2)
{
    if (t < d2v) {
        const bool c1 = t < d1, c0 = t < d0;
        d2v = c1 ? d1 : t;                 i2 = c1 ? i1 : jj;
        const float nd1 = c1 ? (c0 ? d0 : t) : d1;
        const int   ni1 = c1 ? (c0 ? i0 : jj) : i1;
        d1 = nd1;                          i1 = ni1;
        d0 = c0 ? t : d0;                  i0 = c0 ? jj : i0;
    }
}

// packed gold distance for 4 pairs (8 candidates) from staged LDS
__device__ __forceinline__ void dist4(
    const float4* __restrict__ sA, const float4* __restrict__ sB, int p4,
    v2f px2, v2f py2, v2f pz2, v2f s12, v2f m2, v2f tt[4])
{
#pragma clang fp contract(off)
#pragma unroll
    for (int uu = 0; uu < 4; ++uu) {
        const float4 A  = sA[p4 + uu];      // (x0,x1,y0,y1) broadcast
        const float4 Bq = sB[p4 + uu];      // (z0,z1,s0,s1) broadcast
        const v2f x01 = {A.x, A.y};
        const v2f y01 = {A.z, A.w};
        const v2f z01 = {Bq.x, Bq.y};
        const v2f w01 = {Bq.z, Bq.w};
        const v2f zz  = z01 * pz2;                       // pk_mul
        const v2f dot = __builtin_elementwise_fma(px2, x01,
                          __builtin_elementwise_fma(py2, y01, zz));
        const v2f ss  = s12 + w01;                       // pk_add
        tt[uu] = __builtin_elementwise_fma(m2, dot, ss); // pk_fma
    }
}

// ---------------------------------------------------------------------------
// prep: fold BN into conv weights
// ---------------------------------------------------------------------------
__global__ __launch_bounds__(256) void fold_kernel(
    const float* __restrict__ W, const float* __restrict__ bias,
    const float* __restrict__ gamma, const float* __restrict__ beta,
    const float* __restrict__ mean, const float* __restrict__ var,
    float* __restrict__ Wp, float* __restrict__ bp, int Cout, int Cin)
{
    int t = blockIdx.x * 256 + threadIdx.x;
    if (t < Cout * Cin) {
        int o = t / Cin;
        float s = gamma[o] / sqrtf(var[o] + 1e-5f);
        Wp[t] = W[t] * s;
    }
    if (t < Cout) {
        float s = gamma[t] / sqrtf(var[t] + 1e-5f);
        bp[t] = beta[t] + (bias[t] - mean[t]) * s;
    }
}

// ---------------------------------------------------------------------------
// prep: pack p2 pairwise, PLANAR layout for conflict-free staging.
// pair t (cands 2t, 2t+1):  qA[t] = (x0, x1, y0, y1)
//                           qB[t] = (z0, z1, s2_0, s2_1)
// ---------------------------------------------------------------------------
__global__ __launch_bounds__(256) void q4planar_kernel(
    const float* __restrict__ p2, float4* __restrict__ qA,
    float4* __restrict__ qB)
{
    const int t = blockIdx.x * 256 + threadIdx.x;   // pair id < B_*N2_/2
    const float* a = p2 + 6 * (size_t)t;
    const float x0 = a[0], y0 = a[1], z0 = a[2];
    const float x1 = a[3], y1 = a[4], z1 = a[5];
    qA[t] = make_float4(x0, x1, y0, y1);
    qB[t] = make_float4(z0, z1, np_sumsq(x0, y0, z0), np_sumsq(x1, y1, z1));
}

// ---------------------------------------------------------------------------
// f32 tiled GEMM + bias + ReLU.  Y[o][n] = relu( sum_k Wp[o][k] X[k][n] + bp[o] )
// float4 staging; TRANS epilogue via LDS transpose for coalesced 512B writes.
// ---------------------------------------------------------------------------
template <int CIN, bool TRANS>
__global__ __launch_bounds__(256) void gemm_relu_kernel(
    const float* __restrict__ X, const float* __restrict__ Wp,
    const float* __restrict__ bp, float* __restrict__ Y)
{
    __shared__ float A_lds[32][136];  // [k][m]; reused as T[32][132] in epilogue
    __shared__ float B_lds[32][128];  // [k][n]

    const int b  = blockIdx.y;
    const int n0 = blockIdx.x * 128;
    const int tid = threadIdx.x;
    const int ty = tid >> 4;
    const int tx = tid & 15;
    const float* Xb = X + (size_t)b * CIN * N2_;

    float acc[8][8];
#pragma unroll
    for (int i = 0; i < 8; ++i)
#pragma unroll
        for (int j = 0; j < 8; ++j) acc[i][j] = 0.f;

    // float4 staging assignments
    const int a_kq = (tid & 7) * 4;      // k quad within 32
    const int a_r0 = tid >> 3;           // row base, +32 per i  (8 thr = 128B/row)
    const int b_n4 = (tid & 31) * 4;     // n quad  (32 thr = 512B/row)
    const int b_k0 = tid >> 5;           // k row base, +8 per i

    for (int k0 = 0; k0 < CIN; k0 += 32) {
#pragma unroll
        for (int i = 0; i < 4; ++i) {
            const int row = a_r0 + 32 * i;
            const float4 v = *(const float4*)&Wp[(size_t)row * CIN + k0 + a_kq];
            A_lds[a_kq + 0][row] = v.x;
            A_lds[a_kq + 1][row] = v.y;
            A_lds[a_kq + 2][row] = v.z;
            A_lds[a_kq + 3][row] = v.w;
        }
#pragma unroll
        for (int i = 0; i < 4; ++i) {
            const int krow = b_k0 + 8 * i;
            *(float4*)&B_lds[krow][b_n4] =
                *(const float4*)&Xb[(size_t)(k0 + krow) * N2_ + n0 + b_n4];
        }
        __syncthreads();

#pragma unroll
        for (int kk = 0; kk < 32; ++kk) {
            const float4 a0 = *(const float4*)&A_lds[kk][ty * 4];
            const float4 a1 = *(const float4*)&A_lds[kk][64 + ty * 4];
            const float4 bq0 = *(const float4*)&B_lds[kk][tx * 4];
            const float4 bq1 = *(const float4*)&B_lds[kk][64 + tx * 4];
            const float av[8] = {a0.x, a0.y, a0.z, a0.w, a1.x, a1.y, a1.z, a1.w};
            const float bv[8] = {bq0.x, bq0.y, bq0.z, bq0.w, bq1.x, bq1.y, bq1.z, bq1.w};
#pragma unroll
            for (int i = 0; i < 8; ++i)
#pragma unroll
                for (int j = 0; j < 8; ++j)
                    acc[i][j] = fmaf(av[i], bv[j], acc[i][j]);
        }
        __syncthreads();
    }

    float bias_v[8];
#pragma unroll
    for (int i = 0; i < 8; ++i) {
        const int r = (i < 4) ? (ty * 4 + i) : (64 + ty * 4 + (i - 4));
        bias_v[i] = bp[r];
    }

    if (!TRANS) {
#pragma unroll
        for (int i = 0; i < 8; ++i) {
            const int r = (i < 4) ? (ty * 4 + i) : (64 + ty * 4 + (i - 4));
            float* yrow = Y + ((size_t)b * 128 + r) * N2_ + n0;
            float4 v0, v1;
            v0.x = fmaxf(acc[i][0] + bias_v[i], 0.f);
            v0.y = fmaxf(acc[i][1] + bias_v[i], 0.f);
            v0.z = fmaxf(acc[i][2] + bias_v[i], 0.f);
            v0.w = fmaxf(acc[i][3] + bias_v[i], 0.f);
            v1.x = fmaxf(acc[i][4] + bias_v[i], 0.f);
            v1.y = fmaxf(acc[i][5] + bias_v[i], 0.f);
            v1.z = fmaxf(acc[i][6] + bias_v[i], 0.f);
            v1.w = fmaxf(acc[i][7] + bias_v[i], 0.f);
            *(float4*)(yrow + tx * 4) = v0;
            *(float4*)(yrow + 64 + tx * 4) = v1;
        }
    } else {
        // LDS-transposed epilogue: 4 slabs of 32 points; coalesced 512B rows.
        float (*T)[132] = (float(*)[132])&A_lds[0][0];   // 32x132 <= 32x136
#pragma unroll
        for (int s = 0; s < 4; ++s) {
            if ((tx >> 3) == (s & 1)) {
                const int joff = (s >> 1) * 4;
                const int cl0 = (tx & 7) * 4;
#pragma unroll
                for (int i = 0; i < 8; ++i) {
                    const int r = (i < 4) ? (ty * 4 + i) : (64 + ty * 4 + (i - 4));
#pragma unroll
                    for (int j = 0; j < 4; ++j)
                        T[cl0 + j][r] = fmaxf(acc[i][j + joff] + bias_v[i], 0.f);
                }
            }
            __syncthreads();
#pragma unroll
            for (int p = 0; p < 4; ++p) {
                const int row = (tid >> 5) + 8 * p;
                const float4 v = *(const float4*)&T[row][(tid & 31) * 4];
                float* orow = Y + ((size_t)b * N2_ + n0 + 32 * s + row) * 128;
                *(float4*)&orow[(tid & 31) * 4] = v;
            }
            __syncthreads();
        }
    }
}

// ---------------------------------------------------------------------------
// KNN phase 1 (two-pass): block = 256 queries x 1 chunk of 2048 candidates.
// 1024 blocks, 4 waves/SIMD, 32 KB LDS.
// Pass 1: values-only min/max merge network -> exact gold 3rd value thr.
// Pass 2: rescan, wave-any(<=thr) guard, rare-path gold ins3 replay ->
//         bit-exact gold (d,i) partial triple. Partials chunk-major.
// ---------------------------------------------------------------------------
__global__ __launch_bounds__(256, 4) void knn_phase1(
    const float* __restrict__ p1, const float4* __restrict__ qA,
    const float4* __restrict__ qB,
    float* __restrict__ part_d, int* __restrict__ part_i)
{
#pragma clang fp contract(off)
    __shared__ float4 sA[1024];           // 16 KB  (x0,x1,y0,y1) per pair
    __shared__ float4 sB[1024];           // 16 KB  (z0,z1,s0,s1) per pair

    const int tid = threadIdx.x;
    const int chunk = blockIdx.x & 1;
    const int g = (blockIdx.x >> 1) * 256 + tid;   // query id
    const int b = g >> 14;                         // uniform per block

    const float px = p1[3 * (size_t)g + 0];
    const float py = p1[3 * (size_t)g + 1];
    const float pz = p1[3 * (size_t)g + 2];
    const float s1q = np_sumsq(px, py, pz);

    const v2f px2 = {px, px};
    const v2f py2 = {py, py};
    const v2f pz2 = {pz, pz};
    const v2f s12 = {s1q, s1q};
    const v2f m2  = {-2.0f, -2.0f};

    // stage 1024 pairs (2048 cands), planar: contiguous 16B/lane writes
    const float4* gA = qA + (size_t)b * (N2_ / 2) + chunk * 1024;
    const float4* gB = qB + (size_t)b * (N2_ / 2) + chunk * 1024;
#pragma unroll
    for (int i = 0; i < 4; ++i) {
        sA[tid + i * 256] = gA[tid + i * 256];
        sB[tid + i * 256] = gB[tid + i * 256];
    }
    __syncthreads();

    // ---- pass 1: top-3 VALUES only (pure min/max; no cmps, no masks) ----
    float d0 = 1e30f, d1 = 1e30f, d2v = 1e30f;
    for (int p4 = 0; p4 < 1024; p4 += 4) {
        v2f tt[4];
        dist4(sA, sB, p4, px2, py2, pz2, s12, m2, tt);
#pragma unroll
        for (int uu = 0; uu < 4; ++uu) {
            const float t0 = tt[uu].x, t1 = tt[uu].y;
            const float u  = fminf(t0, t1);
            const float v  = fmaxf(t0, t1);
            const float u2 = fmaxf(d0, u);
            d0 = fminf(d0, u);
            const float vv = fminf(d1, v);
            const float ww = fmaxf(d1, v);
            d1 = fminf(u2, vv);
            const float x  = fmaxf(u2, vv);
            d2v = fminf(d2v, fminf(x, ww));     // min3
        }
    }
    const float thr = d2v;   // exact gold 3rd-smallest distance in chunk

    // ---- pass 2: recover indices by gold replay over the <=thr superset ----
    float dd0 = 1e30f, dd1 = 1e30f, dd2 = 1e30f;
    int i0 = 0, i1 = 0, i2 = 0;
    const int jbase = chunk * 2048;
    for (int p4 = 0; p4 < 1024; p4 += 4) {
        v2f tt[4];
        dist4(sA, sB, p4, px2, py2, pz2, s12, m2, tt);
#pragma unroll
        for (int uu = 0; uu < 4; ++uu) {
            const float t0 = tt[uu].x, t1 = tt[uu].y;
            // thr is FINAL -> superset guard is exact; ties included via <=
            if (__any(fminf(t0, t1) <= thr)) {
                const int j0 = jbase + 2 * (p4 + uu);
                ins3(t0, j0,     dd0, dd1, dd2, i0, i1, i2);
                ins3(t1, j0 + 1, dd0, dd1, dd2, i0, i1, i2);
            }
        }
    }

    part_d[(0 * 2 + chunk) * NTOT_ + g] = dd0;
    part_d[(1 * 2 + chunk) * NTOT_ + g] = dd1;
    part_d[(2 * 2 + chunk) * NTOT_ + g] = dd2;
    part_i[(0 * 2 + chunk) * NTOT_ + g] = i0;
    part_i[(1 * 2 + chunk) * NTOT_ + g] = i1;
    part_i[(2 * 2 + chunk) * NTOT_ + g] = i2;
}

// ---------------------------------------------------------------------------
// KNN merge: stable 6-way merge (chunk-major preserves tie order) + gold
// plain-f32 weights.
// ---------------------------------------------------------------------------
__global__ __launch_bounds__(256) void knn_merge(
    const float* __restrict__ part_d, const int* __restrict__ part_i,
    int* __restrict__ idx_ws, float* __restrict__ w_ws)
{
    const int g = blockIdx.x * 256 + threadIdx.x;

    float d0 = 1e30f, d1 = 1e30f, d2v = 1e30f;
    int i0 = 0, i1 = 0, i2 = 0;

#pragma unroll
    for (int c = 0; c < 2; ++c) {
#pragma unroll
        for (int k = 0; k < 3; ++k) {
            const float t = part_d[(k * 2 + c) * NTOT_ + g];
            const int  jj = part_i[(k * 2 + c) * NTOT_ + g];
            if (t < d2v) {
                const bool c1 = t < d1, c0 = t < d0;
                d2v = c1 ? d1 : t;                 i2 = c1 ? i1 : jj;
                const float nd1 = c1 ? (c0 ? d0 : t) : d1;
                const int   ni1 = c1 ? (c0 ? i0 : jj) : i1;
                d1 = nd1;                          i1 = ni1;
                d0 = c0 ? t : d0;                  i0 = c0 ? jj : i0;
            }
        }
    }

    float w0, w1, w2;
    {
#pragma clang fp contract(off)
        const float r0 = 1.0f / (d0 + 1e-8f);
        const float r1 = 1.0f / (d1 + 1e-8f);
        const float r2 = 1.0f / (d2v + 1e-8f);
        const float rs = (r0 + r1) + r2;
        w0 = r0 / rs;
        w1 = r1 / rs;
        w2 = r2 / rs;
    }

    idx_ws[g]             = i0;
    idx_ws[NTOT_ + g]     = i1;
    idx_ws[2 * NTOT_ + g] = i2;
    w_ws[g]               = w0;
    w_ws[NTOT_ + g]       = w1;
    w_ws[2 * NTOT_ + g]   = w2;
}

// ---------------------------------------------------------------------------
// gather + weighted sum: out[b][c][n] = sum_k w_k * f_t[b][idx_k][c]
// nontemporal stores: write-once output must not evict f_t from L2.
// ---------------------------------------------------------------------------
__global__ __launch_bounds__(256) void gather_kernel(
    const float* __restrict__ f_t, const int* __restrict__ idx_ws,
    const float* __restrict__ w_ws, float* __restrict__ out)
{
    const int tid = threadIdx.x;
    const int lane = tid & 63, cg = tid >> 6;
    const int g = blockIdx.x * 64 + lane;
    const int b = g >> 14, n = g & 16383;

    const int i0 = idx_ws[g];
    const int i1 = idx_ws[NTOT_ + g];
    const int i2 = idx_ws[2 * NTOT_ + g];
    const float w0 = w_ws[g];
    const float w1 = w_ws[NTOT_ + g];
    const float w2 = w_ws[2 * NTOT_ + g];

    const float* base = f_t + (size_t)b * N2_ * 128 + cg * 32;
    const float4* r0 = (const float4*)(base + (size_t)i0 * 128);
    const float4* r1 = (const float4*)(base + (size_t)i1 * 128);
    const float4* r2 = (const float4*)(base + (size_t)i2 * 128);

    float acc[32];
#pragma unroll
    for (int q = 0; q < 8; ++q) {
        const float4 a = r0[q], bb = r1[q], c = r2[q];
        acc[4 * q + 0] = fmaf(w0, a.x, fmaf(w1, bb.x, w2 * c.x));
        acc[4 * q + 1] = fmaf(w0, a.y, fmaf(w1, bb.y, w2 * c.y));
        acc[4 * q + 2] = fmaf(w0, a.z, fmaf(w1, bb.z, w2 * c.z));
        acc[4 * q + 3] = fmaf(w0, a.w, fmaf(w1, bb.w, w2 * c.w));
    }

    float* ob = out + ((size_t)b * 128 + cg * 32) * N1_ + n;
#pragma unroll
    for (int c = 0; c < 32; ++c)
        __builtin_nontemporal_store(acc[c], ob + (size_t)c * N1_);
}

// ---------------------------------------------------------------------------
extern "C" void kernel_launch(void* const* d_in, const int* in_sizes, int n_in,
                              void* d_out, int out_size, void* d_ws, size_t ws_size,
                              hipStream_t stream)
{
    const float* p1  = (const float*)d_in[0];
    const float* p2  = (const float*)d_in[1];
    const float* f2  = (const float*)d_in[2];
    const float* W0  = (const float*)d_in[3];
    const float* b0  = (const float*)d_in[4];
    const float* g0  = (const float*)d_in[5];
    const float* be0 = (const float*)d_in[6];
    const float* m0  = (const float*)d_in[7];
    const float* v0  = (const float*)d_in[8];
    const float* W1  = (const float*)d_in[9];
    const float* b1  = (const float*)d_in[10];
    const float* g1  = (const float*)d_in[11];
    const float* be1 = (const float*)d_in[12];
    const float* m1  = (const float*)d_in[13];
    const float* v1  = (const float*)d_in[14];

    char* ws = (char*)d_ws;
    float4* qA  = (float4*)(ws);                         // 256 KB planar (x0,x1,y0,y1)
    float4* qB  = (float4*)(ws + (256 << 10));           // 256 KB planar (z0,z1,s0,s1)
    float*  W0p = (float*)(ws + (512 << 10));            // 128 KB
    float*  b0p = (float*)(ws + (640 << 10));            // .5 KB
    float*  W1p = (float*)(ws + (644 << 10));            // 64 KB
    float*  b1p = (float*)(ws + (708 << 10));            // .5 KB
    float*  h   = (float*)(ws + ((size_t)1 << 20));      // 16 MB [B][128][N2] (dead after gemm2)
    float*  f_t = (float*)(ws + ((size_t)17 << 20));     // 16 MB [B][N2][128]
    int*    idxw= (int*)  (ws + ((size_t)33 << 20));     // 1.5 MB
    float*  wgt = (float*)(ws + ((size_t)35 << 20));     // 1.5 MB
    // KNN partials reuse h's region (dead once gemm2 has run):
    float*  pd  = (float*)(ws + ((size_t)1 << 20));      // 3.1 MB (6 x NTOT)
    int*    pi  = (int*)  (ws + ((size_t)9 << 20));      // 3.1 MB

    fold_kernel<<<128, 256, 0, stream>>>(W0, b0, g0, be0, m0, v0, W0p, b0p, 128, 256);
    fold_kernel<<<64, 256, 0, stream>>>(W1, b1, g1, be1, m1, v1, W1p, b1p, 128, 128);
    q4planar_kernel<<<(B_ * N2_ / 2) / 256, 256, 0, stream>>>(p2, qA, qB);

    gemm_relu_kernel<256, false><<<dim3(32, 8), 256, 0, stream>>>(f2, W0p, b0p, h);
    gemm_relu_kernel<128, true ><<<dim3(32, 8), 256, 0, stream>>>(h, W1p, b1p, f_t);

    knn_phase1<<<(NTOT_ / 256) * 2, 256, 0, stream>>>(p1, qA, qB, pd, pi);
    knn_merge<<<NTOT_ / 256, 256, 0, stream>>>(pd, pi, idxw, wgt);
    gather_kernel<<<NTOT_ / 64, 256, 0, stream>>>(f_t, idxw, wgt, (float*)d_out);
}

// Round 6
// 354.376 us; speedup vs baseline: 1.2825x; 1.2825x over previous
//
#include <hip/hip_runtime.h>

#define B_    8
#define N1_   16384
#define N2_   4096
#define NTOT_ (B_ * N1_)

// ---------------------------------------------------------------------------
// GOLD SEMANTICS (verified R12/R13, absmax 0.015625 = bf16 output floor):
//   s  = ((x*x + y*y) + z*z)          plain forward, no fma
//   dot= fma(x,x', fma(y,y', z*z'))   z-first FMA chain (numpy AVX2 einsum)
//   d2 = fma(-2, dot, s1+s2)          bitwise == plain (s1+s2) - 2*dot
//   w  : r = 1/(d2+1e-8), w = r/((r0+r1)+r2), plain f32
// R20: KNN campaign closed. Measured: R0 scan 155.5us (105% VALUBusy) beats
// fused(193)/guard(163)/network(256)/minmax(268)/two-pass(279). Reverted to
// the R0 kernel verbatim. This round attacks the other ~199us:
//  - GEMMs were 256 blocks = 1 block/CU = 1 wave/SIMD: k-step barrier stalls
//    fully exposed. N-tile 128->64 => 512 blocks, 2 blocks/CU, m114-style
//    cross-block overlap. Same k-order => bit-identical accumulation.
//  - gather: XCD-aligned block swizzle (XCD x <-> batch x; f_t slice 2.1MB
//    fits 4MB XCD L2) + knn_merge folded into gather prologue.
//  - fold0/fold1/q4 fused into one prep kernel. 8 launches -> 5.
// ---------------------------------------------------------------------------
__device__ __forceinline__ float np_sumsq(float x, float y, float z)
{
#pragma clang fp contract(off)
    return ((x * x + y * y) + z * z);   // forward, plain (no contraction)
}

// ---------------------------------------------------------------------------
// fused prep: blocks [0,128) fold layer0; [128,192) fold layer1;
// [192,320) pack q4 = (x, y, z, s2) per candidate.
// ---------------------------------------------------------------------------
__global__ __launch_bounds__(256) void prep_kernel(
    const float* __restrict__ W0, const float* __restrict__ b0,
    const float* __restrict__ g0, const float* __restrict__ be0,
    const float* __restrict__ m0, const float* __restrict__ v0,
    const float* __restrict__ W1, const float* __restrict__ b1,
    const float* __restrict__ g1, const float* __restrict__ be1,
    const float* __restrict__ m1, const float* __restrict__ v1,
    const float* __restrict__ p2,
    float* __restrict__ W0p, float* __restrict__ b0p,
    float* __restrict__ W1p, float* __restrict__ b1p,
    float4* __restrict__ q4)
{
    const int bx = blockIdx.x;
    const int tid = threadIdx.x;
    if (bx < 128) {                       // fold layer0: Cout=128, Cin=256
        const int t = bx * 256 + tid;
        const int o = t >> 8;             // /256
        const float s = g0[o] / sqrtf(v0[o] + 1e-5f);
        W0p[t] = W0[t] * s;
        if (t < 128) {
            const float ss = g0[t] / sqrtf(v0[t] + 1e-5f);
            b0p[t] = be0[t] + (b0[t] - m0[t]) * ss;
        }
    } else if (bx < 192) {                // fold layer1: Cout=128, Cin=128
        const int t = (bx - 128) * 256 + tid;
        const int o = t >> 7;             // /128
        const float s = g1[o] / sqrtf(v1[o] + 1e-5f);
        W1p[t] = W1[t] * s;
        if (t < 128) {
            const float ss = g1[t] / sqrtf(v1[t] + 1e-5f);
            b1p[t] = be1[t] + (b1[t] - m1[t]) * ss;
        }
    } else {                              // q4 pack: t < B_*N2_
        const int t = (bx - 192) * 256 + tid;
        const float x = p2[3 * (size_t)t + 0];
        const float y = p2[3 * (size_t)t + 1];
        const float z = p2[3 * (size_t)t + 2];
        q4[t] = make_float4(x, y, z, np_sumsq(x, y, z));
    }
}

// ---------------------------------------------------------------------------
// f32 tiled GEMM + bias + ReLU.  Y[o][n] = relu( sum_k Wp[o][k] X[k][n] + bp[o] )
// Tile 128M x 64N, acc 8x4, grid 64x8 = 512 blocks = 2 blocks/CU
// (2 waves/SIMD: cross-block overlap hides the k-step staging stall).
// K-accumulation order identical to the proven 128x128 kernel.
// TRANS epilogue: LDS transpose, coalesced 512B rows of f_t.
// ---------------------------------------------------------------------------
template <int CIN, bool TRANS>
__global__ __launch_bounds__(256) void gemm_relu_kernel(
    const float* __restrict__ X, const float* __restrict__ Wp,
    const float* __restrict__ bp, float* __restrict__ Y)
{
    __shared__ float A_lds[32][136];  // [k][m]; reused as T[32][132] in epilogue
    __shared__ float B_lds[32][64];   // [k][n]

    const int b  = blockIdx.y;
    const int n0 = blockIdx.x * 64;
    const int tid = threadIdx.x;
    const int ty = tid >> 4;          // 0..15 -> M rows
    const int tx = tid & 15;          // 0..15 -> N quad tx*4
    const float* Xb = X + (size_t)b * CIN * N2_;

    float acc[8][4];
#pragma unroll
    for (int i = 0; i < 8; ++i)
#pragma unroll
        for (int j = 0; j < 4; ++j) acc[i][j] = 0.f;

    // staging assignments
    const int a_kq = (tid & 7) * 4;      // k quad within 32
    const int a_r0 = tid >> 3;           // A row base, +32 per i
    const int b_n4 = (tid & 15) * 4;     // n quad within 64
    const int b_k0 = tid >> 4;           // k row base, +16 per i

    for (int k0 = 0; k0 < CIN; k0 += 32) {
#pragma unroll
        for (int i = 0; i < 4; ++i) {
            const int row = a_r0 + 32 * i;
            const float4 v = *(const float4*)&Wp[(size_t)row * CIN + k0 + a_kq];
            A_lds[a_kq + 0][row] = v.x;
            A_lds[a_kq + 1][row] = v.y;
            A_lds[a_kq + 2][row] = v.z;
            A_lds[a_kq + 3][row] = v.w;
        }
#pragma unroll
        for (int i = 0; i < 2; ++i) {
            const int krow = b_k0 + 16 * i;
            *(float4*)&B_lds[krow][b_n4] =
                *(const float4*)&Xb[(size_t)(k0 + krow) * N2_ + n0 + b_n4];
        }
        __syncthreads();

#pragma unroll
        for (int kk = 0; kk < 32; ++kk) {
            const float4 a0 = *(const float4*)&A_lds[kk][ty * 4];
            const float4 a1 = *(const float4*)&A_lds[kk][64 + ty * 4];
            const float4 bq = *(const float4*)&B_lds[kk][tx * 4];
            const float av[8] = {a0.x, a0.y, a0.z, a0.w, a1.x, a1.y, a1.z, a1.w};
            const float bv[4] = {bq.x, bq.y, bq.z, bq.w};
#pragma unroll
            for (int i = 0; i < 8; ++i)
#pragma unroll
                for (int j = 0; j < 4; ++j)
                    acc[i][j] = fmaf(av[i], bv[j], acc[i][j]);
        }
        __syncthreads();
    }

    float bias_v[8];
#pragma unroll
    for (int i = 0; i < 8; ++i) {
        const int r = (i < 4) ? (ty * 4 + i) : (64 + ty * 4 + (i - 4));
        bias_v[i] = bp[r];
    }

    if (!TRANS) {
#pragma unroll
        for (int i = 0; i < 8; ++i) {
            const int r = (i < 4) ? (ty * 4 + i) : (64 + ty * 4 + (i - 4));
            float* yrow = Y + ((size_t)b * 128 + r) * N2_ + n0;
            float4 v0;
            v0.x = fmaxf(acc[i][0] + bias_v[i], 0.f);
            v0.y = fmaxf(acc[i][1] + bias_v[i], 0.f);
            v0.z = fmaxf(acc[i][2] + bias_v[i], 0.f);
            v0.w = fmaxf(acc[i][3] + bias_v[i], 0.f);
            *(float4*)(yrow + tx * 4) = v0;
        }
    } else {
        // LDS-transposed epilogue: 2 slabs of 32 points; coalesced 512B rows.
        float (*T)[132] = (float(*)[132])&A_lds[0][0];   // 32x132 <= 32x136
#pragma unroll
        for (int s = 0; s < 2; ++s) {
            if ((tx >> 3) == s) {
                const int cl0 = (tx & 7) * 4;
#pragma unroll
                for (int i = 0; i < 8; ++i) {
                    const int r = (i < 4) ? (ty * 4 + i) : (64 + ty * 4 + (i - 4));
#pragma unroll
                    for (int j = 0; j < 4; ++j)
                        T[cl0 + j][r] = fmaxf(acc[i][j] + bias_v[i], 0.f);
                }
            }
            __syncthreads();
#pragma unroll
            for (int p = 0; p < 4; ++p) {
                const int row = (tid >> 5) + 8 * p;
                const float4 v = *(const float4*)&T[row][(tid & 31) * 4];
                float* orow = Y + ((size_t)b * N2_ + n0 + 32 * s + row) * 128;
                *(float4*)&orow[(tid & 31) * 4] = v;
            }
            __syncthreads();
        }
    }
}

// ---------------------------------------------------------------------------
// KNN phase 1 (R0 verbatim, proven 155.5us @105% VALUBusy): block = 256
// queries x 1 chunk of 1024 candidates; gold d2 scan key; top-3, strict <
// (stable ties, ascending j). Partials out, chunk-major.
// ---------------------------------------------------------------------------
__global__ __launch_bounds__(256, 8) void knn_phase1(
    const float* __restrict__ p1, const float4* __restrict__ q4,
    float* __restrict__ part_d, int* __restrict__ part_i)
{
    __shared__ float4 qs[1024];           // 16 KB
    const int tid = threadIdx.x;
    const int chunk = blockIdx.x & 3;
    const int g = (blockIdx.x >> 2) * 256 + tid;   // query id
    const int b = g >> 14;                         // uniform per block

    const float px = p1[3 * (size_t)g + 0];
    const float py = p1[3 * (size_t)g + 1];
    const float pz = p1[3 * (size_t)g + 2];
    const float s1 = np_sumsq(px, py, pz);

    const float4* qb = q4 + (size_t)b * N2_ + chunk * 1024;
#pragma unroll
    for (int i = 0; i < 4; ++i) qs[tid + i * 256] = qb[tid + i * 256];
    __syncthreads();

    float d0 = 1e30f, d1 = 1e30f, d2v = 1e30f;
    int i0 = 0, i1 = 0, i2 = 0;
    const int jbase = chunk * 1024;

    for (int j = 0; j < 1024; j += 4) {
#pragma unroll
        for (int u = 0; u < 4; ++u) {
            const float4 q = qs[j + u];
            const float dot = __fmaf_rn(px, q.x, __fmaf_rn(py, q.y, __fmul_rn(pz, q.z)));
            const float ss  = s1 + q.w;
            const float t   = __fmaf_rn(-2.0f, dot, ss);
            if (t < d2v) {
                const int jj = jbase + j + u;
                const bool c1 = t < d1, c0 = t < d0;
                d2v = c1 ? d1 : t;                 i2 = c1 ? i1 : jj;
                const float nd1 = c1 ? (c0 ? d0 : t) : d1;
                const int   ni1 = c1 ? (c0 ? i0 : jj) : i1;
                d1 = nd1;                          i1 = ni1;
                d0 = c0 ? t : d0;                  i0 = c0 ? jj : i0;
            }
        }
    }

    part_d[(0 * 4 + chunk) * NTOT_ + g] = d0;
    part_d[(1 * 4 + chunk) * NTOT_ + g] = d1;
    part_d[(2 * 4 + chunk) * NTOT_ + g] = d2v;
    part_i[(0 * 4 + chunk) * NTOT_ + g] = i0;
    part_i[(1 * 4 + chunk) * NTOT_ + g] = i1;
    part_i[(2 * 4 + chunk) * NTOT_ + g] = i2;
}

// ---------------------------------------------------------------------------
// gather + merge: per query, stable 12-way merge of chunk partials (gold
// order) + gold plain-f32 weights, then out[b][c][n] = sum_k w_k*f_t[b][ik][c].
// XCD-aligned swizzle: vb = (bx&7)*256 + (bx>>3) -> XCD x handles batch x
// exactly (f_t slice 2.1MB resident in the 4MB XCD L2).
// All 4 channel-groups of a lane redundantly compute the same merge (L1-hit
// loads); nontemporal stores keep f_t from being evicted.
// ---------------------------------------------------------------------------
__global__ __launch_bounds__(256) void gather_kernel(
    const float* __restrict__ f_t, const float* __restrict__ part_d,
    const int* __restrict__ part_i, float* __restrict__ out)
{
    const int tid = threadIdx.x;
    const int lane = tid & 63, cg = tid >> 6;
    const int vb = (blockIdx.x & 7) * 256 + (blockIdx.x >> 3);  // bijective
    const int g = vb * 64 + lane;
    const int b = g >> 14, n = g & 16383;

    // stable 12-way merge (chunk-major preserves gold tie order)
    float d0 = 1e30f, d1 = 1e30f, d2v = 1e30f;
    int i0 = 0, i1 = 0, i2 = 0;
#pragma unroll
    for (int c = 0; c < 4; ++c) {
#pragma unroll
        for (int k = 0; k < 3; ++k) {
            const float t = part_d[(k * 4 + c) * NTOT_ + g];
            const int  jj = part_i[(k * 4 + c) * NTOT_ + g];
            if (t < d2v) {
                const bool c1 = t < d1, c0 = t < d0;
                d2v = c1 ? d1 : t;                 i2 = c1 ? i1 : jj;
                const float nd1 = c1 ? (c0 ? d0 : t) : d1;
                const int   ni1 = c1 ? (c0 ? i0 : jj) : i1;
                d1 = nd1;                          i1 = ni1;
                d0 = c0 ? t : d0;                  i0 = c0 ? jj : i0;
            }
        }
    }

    float w0, w1, w2;
    {
#pragma clang fp contract(off)
        const float r0 = 1.0f / (d0 + 1e-8f);
        const float r1 = 1.0f / (d1 + 1e-8f);
        const float r2 = 1.0f / (d2v + 1e-8f);
        const float rs = (r0 + r1) + r2;
        w0 = r0 / rs;
        w1 = r1 / rs;
        w2 = r2 / rs;
    }

    const float* base = f_t + (size_t)b * N2_ * 128 + cg * 32;
    const float4* r0v = (const float4*)(base + (size_t)i0 * 128);
    const float4* r1v = (const float4*)(base + (size_t)i1 * 128);
    const float4* r2v = (const float4*)(base + (size_t)i2 * 128);

    float acc[32];
#pragma unroll
    for (int q = 0; q < 8; ++q) {
        const float4 a = r0v[q], bb = r1v[q], c = r2v[q];
        acc[4 * q + 0] = fmaf(w0, a.x, fmaf(w1, bb.x, w2 * c.x));
        acc[4 * q + 1] = fmaf(w0, a.y, fmaf(w1, bb.y, w2 * c.y));
        acc[4 * q + 2] = fmaf(w0, a.z, fmaf(w1, bb.z, w2 * c.z));
        acc[4 * q + 3] = fmaf(w0, a.w, fmaf(w1, bb.w, w2 * c.w));
    }

    float* ob = out + ((size_t)b * 128 + cg * 32) * N1_ + n;
#pragma unroll
    for (int c = 0; c < 32; ++c)
        __builtin_nontemporal_store(acc[c], ob + (size_t)c * N1_);
}

// ---------------------------------------------------------------------------
extern "C" void kernel_launch(void* const* d_in, const int* in_sizes, int n_in,
                              void* d_out, int out_size, void* d_ws, size_t ws_size,
                              hipStream_t stream)
{
    const float* p1  = (const float*)d_in[0];
    const float* p2  = (const float*)d_in[1];
    const float* f2  = (const float*)d_in[2];
    const float* W0  = (const float*)d_in[3];
    const float* b0  = (const float*)d_in[4];
    const float* g0  = (const float*)d_in[5];
    const float* be0 = (const float*)d_in[6];
    const float* m0  = (const float*)d_in[7];
    const float* v0  = (const float*)d_in[8];
    const float* W1  = (const float*)d_in[9];
    const float* b1  = (const float*)d_in[10];
    const float* g1  = (const float*)d_in[11];
    const float* be1 = (const float*)d_in[12];
    const float* m1  = (const float*)d_in[13];
    const float* v1  = (const float*)d_in[14];

    char* ws = (char*)d_ws;
    float4* q4  = (float4*)(ws);                         // 512 KB
    float*  W0p = (float*)(ws + (512 << 10));            // 128 KB
    float*  b0p = (float*)(ws + (640 << 10));            // .5 KB
    float*  W1p = (float*)(ws + (644 << 10));            // 64 KB
    float*  b1p = (float*)(ws + (708 << 10));            // .5 KB
    float*  h   = (float*)(ws + ((size_t)1 << 20));      // 16 MB [B][128][N2] (dead after gemm2)
    float*  f_t = (float*)(ws + ((size_t)17 << 20));     // 16 MB [B][N2][128]
    // KNN partials reuse h's region (dead once gemm2 has run):
    float*  pd  = (float*)(ws + ((size_t)1 << 20));      // 6.29 MB
    int*    pi  = (int*)  (ws + ((size_t)9 << 20));      // 6.29 MB

    prep_kernel<<<320, 256, 0, stream>>>(W0, b0, g0, be0, m0, v0,
                                         W1, b1, g1, be1, m1, v1,
                                         p2, W0p, b0p, W1p, b1p, q4);

    gemm_relu_kernel<256, false><<<dim3(64, 8), 256, 0, stream>>>(f2, W0p, b0p, h);
    gemm_relu_kernel<128, true ><<<dim3(64, 8), 256, 0, stream>>>(h, W1p, b1p, f_t);

    knn_phase1<<<(NTOT_ / 256) * 4, 256, 0, stream>>>(p1, q4, pd, pi);
    gather_kernel<<<NTOT_ / 64, 256, 0, stream>>>(f_t, pd, pi, (float*)d_out);
}